// Round 1
// baseline (488.034 us; speedup 1.0000x reference)
//
#include <hip/hip_runtime.h>
#include <hip/hip_bf16.h>

// Problem constants (fixed by the reference): H=256, B=512 graphs, N=200000 nodes, 3 steps.
#define HID 256
#define NG 512
#define CHUNK 32   // nodes per LDS staging chunk (32 * 1KB = 32KB per buffer)

__device__ __forceinline__ float sigmoidf(float v) { return 1.f / (1.f + __expf(-v)); }

__device__ __forceinline__ void load_lds16(const void* g, void* l) {
    __builtin_amdgcn_global_load_lds(
        (const __attribute__((address_space(1))) void*)g,
        (__attribute__((address_space(3))) void*)l, 16, 0, 0);
}

// ---------------------------------------------------------------------------
// prep: Wcat[j][k] = W_ih[j][k] + (k<256 ? W_hh[j][k] : 0);  bcat = b_ih + b_hh
__global__ __launch_bounds__(256) void prep_kernel(
    const float* __restrict__ W_ih, const float* __restrict__ W_hh,
    const float* __restrict__ b_ih, const float* __restrict__ b_hh,
    float* __restrict__ Wcat, float* __restrict__ bcat)
{
    int idx = blockIdx.x * 256 + threadIdx.x;
    if (idx < 1024 * 512) {
        int k = idx & 511;
        float v = W_ih[idx];
        if (k < 256) v += W_hh[(idx >> 9) * 256 + k];
        Wcat[idx] = v;
    }
    if (idx < 1024) bcat[idx] = b_ih[idx] + b_hh[idx];
}

// ---------------------------------------------------------------------------
// starts[g] = lower_bound(batch, g); starts[NG] = n   (batch is sorted)
__global__ __launch_bounds__(256) void find_starts(
    const int* __restrict__ batch, int n, int* __restrict__ starts)
{
    int g = blockIdx.x * 256 + threadIdx.x;
    if (g > NG) return;
    if (g == NG) { starts[NG] = n; return; }
    int lo = 0, hi = n;
    while (lo < hi) {
        int mid = (lo + hi) >> 1;
        if (batch[mid] < g) lo = mid + 1; else hi = mid;
    }
    starts[g] = lo;
}

// ---------------------------------------------------------------------------
// LSTM cell (PyTorch gate order i,f,g,o). step0: gates = bcat, c_prev = 0.
// Writes hs into qs[:, 0:256] (q_star = [hs, r], qs is [NG][512]).
__global__ __launch_bounds__(256) void lstm_cell(
    const float* __restrict__ gates, const float* __restrict__ bcat,
    float* __restrict__ cs, float* __restrict__ qs, int step0)
{
    int b = blockIdx.x, t = threadIdx.x;
    float ig, fg, gg, og, c_prev;
    if (step0) {
        ig = bcat[t]; fg = bcat[256 + t]; gg = bcat[512 + t]; og = bcat[768 + t];
        c_prev = 0.f;
    } else {
        const float* gr = gates + (size_t)b * 1024;
        ig = gr[t]; fg = gr[256 + t]; gg = gr[512 + t]; og = gr[768 + t];
        c_prev = cs[b * HID + t];
    }
    float c_new = sigmoidf(fg) * c_prev + sigmoidf(ig) * tanhf(gg);
    float h = sigmoidf(og) * tanhf(c_new);
    cs[b * HID + t] = c_new;
    qs[b * 512 + t] = h;
}

// ---------------------------------------------------------------------------
// Attention + segment softmax + weighted readout, one block per graph.
// Online softmax over node chunks staged global->LDS (async, double-buffered).
__global__ __launch_bounds__(256) void attention_kernel(
    const float* __restrict__ x, const int* __restrict__ starts,
    float* __restrict__ qs)
{
    __shared__ __align__(16) float xl[2][CHUNK * HID];   // 2 x 32KB
    __shared__ float ql[HID];
    __shared__ float e_arr[CHUNK];
    __shared__ float p_arr[CHUNK];
    __shared__ float m_s, s_s, a_s;

    const int g = blockIdx.x;
    const int tid = threadIdx.x;
    const int s0 = starts[g];
    const int nn = starts[g + 1] - s0;

    ql[tid] = qs[g * 512 + tid];              // q = hs (written by lstm_cell)
    if (tid == 0) { m_s = -3.402823466e38f; s_s = 0.f; a_s = 0.f; }
    float r_t = 0.f;
    __syncthreads();

    const int j = tid >> 3;       // node within chunk owned for e-calc (0..31)
    const int s = tid & 7;        // 32-elem segment within row (rotated access)
    const int lane = tid & 63;
    const int w = tid >> 6;

    // Pre-permute q fragment into registers: qreg[k] = ql[s + 8*((k+j)&31)]
    float qreg[32];
    #pragma unroll
    for (int k = 0; k < 32; ++k) qreg[k] = ql[s + 8 * ((k + j) & 31)];

    if (nn > 0) {
        const char* src = (const char*)x + (size_t)s0 * (HID * 4);
        const int nchunks = (nn + CHUNK - 1) / CHUNK;

        // prefetch chunk 0
        {
            int bytes = (nn < CHUNK ? nn : CHUNK) * 1024;
            #pragma unroll
            for (int i = 0; i < 8; ++i) {
                int offw = i * 4096 + w * 1024;                 // wave-uniform
                int offc = offw < bytes - 1024 ? offw : bytes - 1024;
                load_lds16(src + offc + lane * 16,
                           (char*)&xl[0][0] + offw + lane * 16);
            }
        }

        for (int c = 0; c < nchunks; ++c) {
            const int buf = c & 1;
            int rem = nn - c * CHUNK;
            const int nnc = rem < CHUNK ? rem : CHUNK;
            if (c + 1 < nchunks) {
                const char* src2 = src + (size_t)(c + 1) * (CHUNK * 1024);
                int rem2 = nn - (c + 1) * CHUNK;
                int bytes = (rem2 < CHUNK ? rem2 : CHUNK) * 1024;
                char* dst = (char*)&xl[buf ^ 1][0];
                #pragma unroll
                for (int i = 0; i < 8; ++i) {
                    int offw = i * 4096 + w * 1024;
                    int offc = offw < bytes - 1024 ? offw : bytes - 1024;
                    load_lds16(src2 + offc + lane * 16, dst + offw + lane * 16);
                }
                // wait for chunk c's 8 loads; keep the 8 just-issued in flight
                asm volatile("s_waitcnt vmcnt(8)" ::: "memory");
            } else {
                asm volatile("s_waitcnt vmcnt(0)" ::: "memory");
            }
            asm volatile("s_barrier" ::: "memory");

            // e-calc: 8 threads per node, rotated columns (2-way banks = free)
            const float* xb = &xl[buf][0];
            float acc = 0.f;
            #pragma unroll
            for (int k = 0; k < 32; ++k) {
                int col = s + 8 * ((k + j) & 31);
                acc += xb[j * HID + col] * qreg[k];
            }
            acc += __shfl_xor(acc, 1);
            acc += __shfl_xor(acc, 2);
            acc += __shfl_xor(acc, 4);
            if (s == 0) e_arr[j] = acc;
            asm volatile("s_waitcnt lgkmcnt(0)\n\ts_barrier" ::: "memory");

            // online-softmax scalar update (wave 0)
            if (tid < 64) {
                float e = (tid < nnc) ? e_arr[tid] : -3.402823466e38f;
                float cm = e;
                #pragma unroll
                for (int o = 32; o; o >>= 1) cm = fmaxf(cm, __shfl_xor(cm, o));
                float m_old = m_s;
                float m_new = fmaxf(m_old, cm);
                float al = __expf(m_old - m_new);
                float p = (tid < nnc) ? __expf(e - m_new) : 0.f;
                if (tid < CHUNK) p_arr[tid] = p;
                float ps = p;
                #pragma unroll
                for (int o = 32; o; o >>= 1) ps += __shfl_xor(ps, o);
                if (tid == 0) { s_s = s_s * al + ps; m_s = m_new; a_s = al; }
            }
            asm volatile("s_waitcnt lgkmcnt(0)\n\ts_barrier" ::: "memory");

            // rescale + accumulate r (thread t owns component t; banks distinct)
            float al = a_s;
            r_t *= al;
            for (int jj = 0; jj < nnc; ++jj)
                r_t += p_arr[jj] * xb[jj * HID + tid];
            asm volatile("s_waitcnt lgkmcnt(0)\n\ts_barrier" ::: "memory");
        }
    }
    float denom = (nn > 0) ? s_s : 1.f;
    qs[g * 512 + HID + tid] = r_t / denom;    // r into q_star[:, 256:512]
}

// ---------------------------------------------------------------------------
// C[M x N] = A[M x K] * B[N x K]^T + bias ; BM=64, BN=32, TM=4, TN=2, BK=32
__global__ __launch_bounds__(256) void gemm_bias(
    const float* __restrict__ A, int lda,
    const float* __restrict__ B, int ldb,
    const float* __restrict__ bias,
    float* __restrict__ C, int ldc, int K)
{
    __shared__ float As[64][33];
    __shared__ float Bs[32][33];
    const int tid = threadIdx.x;
    const int m0 = blockIdx.y * 64;
    const int n0 = blockIdx.x * 32;
    const int tx = tid & 15, ty = tid >> 4;
    float acc[4][2] = {};

    for (int k0 = 0; k0 < K; k0 += 32) {
        #pragma unroll
        for (int i = 0; i < 2; ++i) {
            int idx = tid + i * 256;
            int r = idx >> 3, cc = (idx & 7) * 4;
            const float4 v = *(const float4*)&A[(size_t)(m0 + r) * lda + k0 + cc];
            As[r][cc] = v.x; As[r][cc + 1] = v.y; As[r][cc + 2] = v.z; As[r][cc + 3] = v.w;
        }
        {
            int r = tid >> 3, cc = (tid & 7) * 4;
            const float4 v = *(const float4*)&B[(size_t)(n0 + r) * ldb + k0 + cc];
            Bs[r][cc] = v.x; Bs[r][cc + 1] = v.y; Bs[r][cc + 2] = v.z; Bs[r][cc + 3] = v.w;
        }
        __syncthreads();
        #pragma unroll
        for (int kk = 0; kk < 32; ++kk) {
            float b0 = Bs[tx * 2][kk], b1 = Bs[tx * 2 + 1][kk];
            float a0 = As[ty * 4][kk],     a1 = As[ty * 4 + 1][kk];
            float a2 = As[ty * 4 + 2][kk], a3 = As[ty * 4 + 3][kk];
            acc[0][0] += a0 * b0; acc[0][1] += a0 * b1;
            acc[1][0] += a1 * b0; acc[1][1] += a1 * b1;
            acc[2][0] += a2 * b0; acc[2][1] += a2 * b1;
            acc[3][0] += a3 * b0; acc[3][1] += a3 * b1;
        }
        __syncthreads();
    }
    float bb0 = bias[n0 + tx * 2], bb1 = bias[n0 + tx * 2 + 1];
    #pragma unroll
    for (int i = 0; i < 4; ++i) {
        int row = m0 + ty * 4 + i;
        float* cr = &C[(size_t)row * ldc + n0 + tx * 2];
        cr[0] = acc[i][0] + bb0;
        cr[1] = acc[i][1] + bb1;
    }
}

// ---------------------------------------------------------------------------
extern "C" void kernel_launch(void* const* d_in, const int* in_sizes, int n_in,
                              void* d_out, int out_size, void* d_ws, size_t ws_size,
                              hipStream_t stream)
{
    const float* x     = (const float*)d_in[0];
    const int*   batch = (const int*)d_in[1];
    const float* W_ih  = (const float*)d_in[2];
    const float* W_hh  = (const float*)d_in[3];
    const float* b_ih  = (const float*)d_in[4];
    const float* b_hh  = (const float*)d_in[5];
    const float* W_out = (const float*)d_in[6];
    const float* b_out = (const float*)d_in[7];
    float* out = (float*)d_out;
    const int n = in_sizes[1];

    char* ws = (char*)d_ws;
    float* qs     = (float*)(ws);                 // [512][512]  q_star = [hs | r]
    float* cs     = (float*)(ws + 1048576);       // [512][256]
    float* gates  = (float*)(ws + 1572864);       // [512][1024]
    float* Wcat   = (float*)(ws + 3670016);       // [1024][512]
    float* bcat   = (float*)(ws + 5767168);       // [1024]
    int*   starts = (int*)  (ws + 5771264);       // [513]

    prep_kernel<<<2048, 256, 0, stream>>>(W_ih, W_hh, b_ih, b_hh, Wcat, bcat);
    find_starts<<<3, 256, 0, stream>>>(batch, n, starts);

    for (int step = 0; step < 3; ++step) {
        if (step > 0) {
            // gates[512x1024] = qs[512x512] @ Wcat^T + bcat
            gemm_bias<<<dim3(32, 8), 256, 0, stream>>>(qs, 512, Wcat, 512, bcat,
                                                       gates, 1024, 512);
        }
        lstm_cell<<<NG, 256, 0, stream>>>(gates, bcat, cs, qs, step == 0);
        attention_kernel<<<NG, 256, 0, stream>>>(x, starts, qs);
    }
    // out[512x256] = qs[512x512] @ W_out^T + b_out
    gemm_bias<<<dim3(8, 8), 256, 0, stream>>>(qs, 512, W_out, 512, b_out,
                                              out, 256, 512);
}

// Round 2
// 420.303 us; speedup vs baseline: 1.1611x; 1.1611x over previous
//
#include <hip/hip_runtime.h>
#include <hip/hip_bf16.h>

// H=256, B=512 graphs, N=200000 nodes, 3 steps.
#define HID 256
#define NG 512
#define CHUNK 32   // nodes per LDS chunk (32 KB per buffer)

__device__ __forceinline__ float sigmoidf_(float v) { return 1.f / (1.f + __expf(-v)); }

__device__ __forceinline__ void load_lds16(const void* g, void* l) {
    __builtin_amdgcn_global_load_lds(
        (const __attribute__((address_space(1))) void*)g,
        (__attribute__((address_space(3))) void*)l, 16, 0, 0);
}

// ---------------------------------------------------------------------------
// Wcat[j][k] = W_ih[j][k] + (k<256 ? W_hh[j][k] : 0);  bcat = b_ih + b_hh
__global__ __launch_bounds__(256) void prep_kernel(
    const float* __restrict__ W_ih, const float* __restrict__ W_hh,
    const float* __restrict__ b_ih, const float* __restrict__ b_hh,
    float* __restrict__ Wcat, float* __restrict__ bcat)
{
    int idx = blockIdx.x * 256 + threadIdx.x;
    if (idx < 1024 * 512) {
        int k = idx & 511;
        float v = W_ih[idx];
        if (k < 256) v += W_hh[(idx >> 9) * 256 + k];
        Wcat[idx] = v;
    }
    if (idx < 1024) bcat[idx] = b_ih[idx] + b_hh[idx];
}

// ---------------------------------------------------------------------------
__global__ __launch_bounds__(256) void find_starts(
    const int* __restrict__ batch, int n, int* __restrict__ starts)
{
    int g = blockIdx.x * 256 + threadIdx.x;
    if (g > NG) return;
    if (g == NG) { starts[NG] = n; return; }
    int lo = 0, hi = n;
    while (lo < hi) {
        int mid = (lo + hi) >> 1;
        if (batch[mid] < g) lo = mid + 1; else hi = mid;
    }
    starts[g] = lo;
}

// ---------------------------------------------------------------------------
// Fused LSTM cell + attention (online softmax) + readout. One block per graph.
// gp0/gp1 are split-K gate partials; gates = gp0+gp1+bcat.
__global__ __launch_bounds__(256) void attn_kernel(
    const float* __restrict__ x, const int* __restrict__ starts,
    const float* __restrict__ gp0, const float* __restrict__ gp1,
    const float* __restrict__ bcat, float* __restrict__ cs,
    float* __restrict__ qs, int step0)
{
    __shared__ __align__(16) float xl[2][CHUNK * HID];   // 64 KB
    __shared__ __align__(16) float ql[HID];
    __shared__ float e_arr[CHUNK];

    const int g = blockIdx.x;
    const int tid = threadIdx.x;
    const int lane = tid & 63;

    // ---- LSTM cell for hidden unit `tid` (gate order i,f,g,o)
    float ig, fg, gg, og, cp;
    if (step0) {
        ig = bcat[tid]; fg = bcat[256 + tid]; gg = bcat[512 + tid]; og = bcat[768 + tid];
        cp = 0.f;
    } else {
        const float* a0 = gp0 + (size_t)g * 1024;
        const float* a1 = gp1 + (size_t)g * 1024;
        ig = a0[tid]       + a1[tid]       + bcat[tid];
        fg = a0[256 + tid] + a1[256 + tid] + bcat[256 + tid];
        gg = a0[512 + tid] + a1[512 + tid] + bcat[512 + tid];
        og = a0[768 + tid] + a1[768 + tid] + bcat[768 + tid];
        cp = cs[g * HID + tid];
    }
    float cn = sigmoidf_(fg) * cp + sigmoidf_(ig) * tanhf(gg);
    float h  = sigmoidf_(og) * tanhf(cn);
    cs[g * HID + tid] = cn;
    qs[(size_t)g * 512 + tid] = h;     // q_star[:, :256] = hs
    ql[tid] = h;

    const int s0 = starts[g];
    const int nn = starts[g + 1] - s0;
    if (nn <= 0) { qs[(size_t)g * 512 + HID + tid] = 0.f; return; }

    const int j = tid >> 3;        // row slot within chunk (0..31)
    const int s = tid & 7;         // column-group (32 floats each)
    const int row = lane & 31;
    const int w = tid >> 6;

    const int nchunks = (nn + CHUNK - 1) / CHUNK;
    const int tail = nn - (nchunks - 1) * CHUNK;   // 1..32

    // Zero tail rows of the last buffer ONLY if its first use is the last chunk
    // (otherwise stale-but-finite x data sits there and p=0 kills it; DMA never
    // writes past `bytes`, so no race in the nchunks<=2 case).
    if (nchunks <= 2 && tail < CHUNK) {
        float4 z = make_float4(0.f, 0.f, 0.f, 0.f);
        int base = (nchunks - 1) & 1;
        int cnt = (CHUNK - tail) * HID;
        for (int off = tid * 4; off < cnt; off += 1024)
            *(float4*)&xl[base][tail * HID + off] = z;
    }

    const char* src = (const char*)x + (size_t)s0 * 1024;

    // prefetch chunk 0
    {
        int bytes = (nn < CHUNK ? nn : CHUNK) * 1024;
        #pragma unroll
        for (int i = 0; i < 8; ++i) {
            int offw = i * 4096 + w * 1024;               // wave-uniform
            int offc = offw < bytes - 1024 ? offw : bytes - 1024;
            load_lds16(src + offc + lane * 16, (char*)&xl[0][0] + offw + lane * 16);
        }
    }
    // ql + tail zeros visible to all
    asm volatile("s_waitcnt lgkmcnt(0)\n\ts_barrier" ::: "memory");

    // q fragment: cols {s*4 + 32k + i}
    float4 qf[8];
    #pragma unroll
    for (int k = 0; k < 8; ++k) qf[k] = *(const float4*)&ql[k * 32 + s * 4];

    float m_run = -3.402823466e38f, l_run = 0.f;
    float4 racc[8] = {};

    for (int c = 0; c < nchunks; ++c) {
        const int buf = c & 1;
        int rem = nn - c * CHUNK;
        const int nnc = rem < CHUNK ? rem : CHUNK;
        if (c + 1 < nchunks) {
            const char* src2 = src + (size_t)(c + 1) * (CHUNK * 1024);
            int rem2 = nn - (c + 1) * CHUNK;
            int bytes = (rem2 < CHUNK ? rem2 : CHUNK) * 1024;
            char* dst = (char*)&xl[buf ^ 1][0];
            #pragma unroll
            for (int i = 0; i < 8; ++i) {
                int offw = i * 4096 + w * 1024;
                int offc = offw < bytes - 1024 ? offw : bytes - 1024;
                load_lds16(src2 + offc + lane * 16, dst + offw + lane * 16);
            }
            asm volatile("s_waitcnt vmcnt(8)" ::: "memory");   // chunk c landed
        } else {
            asm volatile("s_waitcnt vmcnt(0)" ::: "memory");
        }
        asm volatile("s_barrier" ::: "memory");

        // load row j once (b128, 2-way banks = free); reuse for e AND r
        const float* xb = &xl[buf][0];
        float4 xr[8];
        #pragma unroll
        for (int k = 0; k < 8; ++k) xr[k] = *(const float4*)&xb[j * HID + k * 32 + s * 4];

        float e = 0.f;
        #pragma unroll
        for (int k = 0; k < 8; ++k)
            e += xr[k].x * qf[k].x + xr[k].y * qf[k].y + xr[k].z * qf[k].z + xr[k].w * qf[k].w;
        e += __shfl_xor(e, 1); e += __shfl_xor(e, 2); e += __shfl_xor(e, 4);
        if (s == 0) e_arr[j] = e;
        asm volatile("s_waitcnt lgkmcnt(0)\n\ts_barrier" ::: "memory");

        // replicated online-softmax update (identical arithmetic in all threads)
        float eL = (row < nnc) ? e_arr[row] : -3.402823466e38f;
        float mc = eL;
        #pragma unroll
        for (int o = 16; o; o >>= 1) mc = fmaxf(mc, __shfl_xor(mc, o));
        float m_new = fmaxf(m_run, mc);
        float alpha = __expf(m_run - m_new);
        float pL = (row < nnc) ? __expf(eL - m_new) : 0.f;
        float ps = pL;
        #pragma unroll
        for (int o = 16; o; o >>= 1) ps += __shfl_xor(ps, o);
        l_run = l_run * alpha + ps;
        m_run = m_new;
        float p = __shfl(pL, j);        // p for my row slot

        #pragma unroll
        for (int k = 0; k < 8; ++k) {
            racc[k].x = racc[k].x * alpha + p * xr[k].x;
            racc[k].y = racc[k].y * alpha + p * xr[k].y;
            racc[k].z = racc[k].z * alpha + p * xr[k].z;
            racc[k].w = racc[k].w * alpha + p * xr[k].w;
        }
    }

    // cross-row-slot reduction through LDS (reuse xl[0])
    asm volatile("s_waitcnt lgkmcnt(0)\n\ts_barrier" ::: "memory");
    float* red = &xl[0][0];
    #pragma unroll
    for (int k = 0; k < 8; ++k)
        *(float4*)&red[j * HID + k * 32 + s * 4] = racc[k];
    asm volatile("s_waitcnt lgkmcnt(0)\n\ts_barrier" ::: "memory");
    float sum = 0.f;
    #pragma unroll
    for (int jj = 0; jj < 32; ++jj) sum += red[jj * HID + tid];
    qs[(size_t)g * 512 + HID + tid] = sum / l_run;   // q_star[:, 256:512] = r
}

// ---------------------------------------------------------------------------
// Cp[z][M x N] = A[M x K-slice] * B[N x K-slice]^T ; 64x64 tile, 4x4 micro,
// b128 LDS reads both operands, global prefetch. grid (N/64, M/64, S).
__global__ __launch_bounds__(256) void gemm_splitk(
    const float* __restrict__ A, int lda,
    const float* __restrict__ B, int ldb,
    float* __restrict__ Cp, int ldc, int KS, size_t slice_stride)
{
    __shared__ float As[16][76];   // pad 76: write banks 2-way, rows 16B-aligned
    __shared__ float Bs[16][76];
    const int tid = threadIdx.x;
    const int tx = tid & 15, ty = tid >> 4;
    const int m0 = blockIdx.y * 64, n0 = blockIdx.x * 64;
    const int kb = blockIdx.z * KS;
    const int r = tid >> 2, kc = (tid & 3) << 2;
    float acc[4][4] = {};

    const float* Ap = &A[(size_t)(m0 + r) * lda + kb + kc];
    const float* Bp = &B[(size_t)(n0 + r) * ldb + kb + kc];
    float4 av = *(const float4*)Ap;
    float4 bv = *(const float4*)Bp;

    for (int k0 = 0; k0 < KS; k0 += 16) {
        As[kc + 0][r] = av.x; As[kc + 1][r] = av.y; As[kc + 2][r] = av.z; As[kc + 3][r] = av.w;
        Bs[kc + 0][r] = bv.x; Bs[kc + 1][r] = bv.y; Bs[kc + 2][r] = bv.z; Bs[kc + 3][r] = bv.w;
        __syncthreads();
        if (k0 + 16 < KS) {
            av = *(const float4*)(Ap + k0 + 16);
            bv = *(const float4*)(Bp + k0 + 16);
        }
        #pragma unroll
        for (int kk = 0; kk < 16; ++kk) {
            float4 a = *(const float4*)&As[kk][ty << 2];
            float4 b = *(const float4*)&Bs[kk][tx << 2];
            acc[0][0] += a.x * b.x; acc[0][1] += a.x * b.y; acc[0][2] += a.x * b.z; acc[0][3] += a.x * b.w;
            acc[1][0] += a.y * b.x; acc[1][1] += a.y * b.y; acc[1][2] += a.y * b.z; acc[1][3] += a.y * b.w;
            acc[2][0] += a.z * b.x; acc[2][1] += a.z * b.y; acc[2][2] += a.z * b.z; acc[2][3] += a.z * b.w;
            acc[3][0] += a.w * b.x; acc[3][1] += a.w * b.y; acc[3][2] += a.w * b.z; acc[3][3] += a.w * b.w;
        }
        __syncthreads();
    }
    float* out = Cp + blockIdx.z * slice_stride;
    #pragma unroll
    for (int i = 0; i < 4; ++i) {
        float4 o = make_float4(acc[i][0], acc[i][1], acc[i][2], acc[i][3]);
        *(float4*)&out[(size_t)(m0 + ty * 4 + i) * ldc + n0 + (tx << 2)] = o;
    }
}

// ---------------------------------------------------------------------------
// out[512x256] = sum of 4 K-slices + b_out
__global__ __launch_bounds__(256) void finalize_out(
    const float* __restrict__ op, const float* __restrict__ b_out,
    float* __restrict__ out)
{
    int i = blockIdx.x * 256 + threadIdx.x;
    if (i < 512 * 256) {
        float v = op[i] + op[131072 + i] + op[262144 + i] + op[393216 + i] + b_out[i & 255];
        out[i] = v;
    }
}

// ---------------------------------------------------------------------------
extern "C" void kernel_launch(void* const* d_in, const int* in_sizes, int n_in,
                              void* d_out, int out_size, void* d_ws, size_t ws_size,
                              hipStream_t stream)
{
    const float* x     = (const float*)d_in[0];
    const int*   batch = (const int*)d_in[1];
    const float* W_ih  = (const float*)d_in[2];
    const float* W_hh  = (const float*)d_in[3];
    const float* b_ih  = (const float*)d_in[4];
    const float* b_hh  = (const float*)d_in[5];
    const float* W_out = (const float*)d_in[6];
    const float* b_out = (const float*)d_in[7];
    float* out = (float*)d_out;
    const int n = in_sizes[1];
    (void)n_in; (void)out_size; (void)ws_size;

    char* ws = (char*)d_ws;
    float* qs      = (float*)(ws);                  // [512][512]
    float* cs      = (float*)(ws + 0x100000);       // [512][256]
    float* gates_p = (float*)(ws + 0x180000);       // [2][512][1024]
    float* Wcat    = (float*)(ws + 0x580000);       // [1024][512]
    float* bcat    = (float*)(ws + 0x780000);       // [1024]
    int*   starts  = (int*)  (ws + 0x781000);       // [513]
    float* out_p   = (float*)(ws + 0x790000);       // [4][512][256]

    prep_kernel<<<2048, 256, 0, stream>>>(W_ih, W_hh, b_ih, b_hh, Wcat, bcat);
    find_starts<<<3, 256, 0, stream>>>(batch, n, starts);

    for (int step = 0; step < 3; ++step) {
        if (step > 0) {
            // gates_p[z] = qs[512x512] @ Wcat[:, z*256:(z+1)*256]^T ; z=0,1
            gemm_splitk<<<dim3(16, 8, 2), 256, 0, stream>>>(
                qs, 512, Wcat, 512, gates_p, 1024, 256, (size_t)512 * 1024);
        }
        attn_kernel<<<NG, 256, 0, stream>>>(
            x, starts, gates_p, gates_p + (size_t)512 * 1024, bcat, cs, qs, step == 0);
    }
    // out_p[z] = qs @ W_out^T slices ; then finalize adds bias
    gemm_splitk<<<dim3(4, 8, 4), 256, 0, stream>>>(
        qs, 512, W_out, 512, out_p, 256, 128, (size_t)512 * 256);
    finalize_out<<<512, 256, 0, stream>>>(out_p, b_out, out);
}

// Round 3
// 413.503 us; speedup vs baseline: 1.1802x; 1.0164x over previous
//
#include <hip/hip_runtime.h>
#include <hip/hip_bf16.h>

// H=256, B=512 graphs, N=200000 nodes, 3 steps.
#define HID 256
#define NG 512

__device__ __forceinline__ float sigmoidf_(float v) { return 1.f / (1.f + __expf(-v)); }

// ---------------------------------------------------------------------------
// Wcat[j][k] = W_ih[j][k] + (k<256 ? W_hh[j][k] : 0);  bcat = b_ih + b_hh
__global__ __launch_bounds__(256) void prep_kernel(
    const float* __restrict__ W_ih, const float* __restrict__ W_hh,
    const float* __restrict__ b_ih, const float* __restrict__ b_hh,
    float* __restrict__ Wcat, float* __restrict__ bcat)
{
    int idx = blockIdx.x * 256 + threadIdx.x;
    if (idx < 1024 * 512) {
        int k = idx & 511;
        float v = W_ih[idx];
        if (k < 256) v += W_hh[(idx >> 9) * 256 + k];
        Wcat[idx] = v;
    }
    if (idx < 1024) bcat[idx] = b_ih[idx] + b_hh[idx];
}

// ---------------------------------------------------------------------------
__global__ __launch_bounds__(256) void find_starts(
    const int* __restrict__ batch, int n, int* __restrict__ starts)
{
    int g = blockIdx.x * 256 + threadIdx.x;
    if (g > NG) return;
    if (g == NG) { starts[NG] = n; return; }
    int lo = 0, hi = n;
    while (lo < hi) {
        int mid = (lo + hi) >> 1;
        if (batch[mid] < g) lo = mid + 1; else hi = mid;
    }
    starts[g] = lo;
}

// ---------------------------------------------------------------------------
// Fused LSTM cell + attention + readout. One block per graph.
// Barrier-free main loop: wave w owns 8-row chunks c ≡ w (mod 4), keeps a
// private online-softmax state (m,l,racc) entirely in registers, direct
// coalesced global loads (no LDS staging). 4 wave-states merged at the end.
__global__ __launch_bounds__(256) void attn_kernel(
    const float* __restrict__ x, const int* __restrict__ starts,
    const float* __restrict__ gp0, const float* __restrict__ gp1,
    const float* __restrict__ bcat, float* __restrict__ cs,
    float* __restrict__ qs, int step0)
{
    __shared__ __align__(16) float ql[HID];
    __shared__ __align__(16) float red[4][HID];
    __shared__ float mw[4], lw[4];

    const int g = blockIdx.x;
    const int tid = threadIdx.x;

    // ---- LSTM cell for hidden unit `tid` (gate order i,f,g,o)
    float ig, fg, gg, og, cp;
    if (step0) {
        ig = bcat[tid]; fg = bcat[256 + tid]; gg = bcat[512 + tid]; og = bcat[768 + tid];
        cp = 0.f;
    } else {
        const float* a0 = gp0 + (size_t)g * 1024;
        const float* a1 = gp1 + (size_t)g * 1024;
        ig = a0[tid]       + a1[tid]       + bcat[tid];
        fg = a0[256 + tid] + a1[256 + tid] + bcat[256 + tid];
        gg = a0[512 + tid] + a1[512 + tid] + bcat[512 + tid];
        og = a0[768 + tid] + a1[768 + tid] + bcat[768 + tid];
        cp = cs[g * HID + tid];
    }
    float cn = sigmoidf_(fg) * cp + sigmoidf_(ig) * tanhf(gg);
    float h  = sigmoidf_(og) * tanhf(cn);
    cs[g * HID + tid] = cn;
    qs[(size_t)g * 512 + tid] = h;      // q_star[:, :256] = hs
    ql[tid] = h;

    const int s0 = starts[g];
    const int nn = starts[g + 1] - s0;
    if (nn <= 0) { qs[(size_t)g * 512 + HID + tid] = 0.f; return; }
    __syncthreads();

    const int w = tid >> 6, lane = tid & 63;
    const int j = lane >> 3;        // row within 8-row chunk
    const int s = lane & 7;         // 16B column-group within row

    float4 qf[8];
    #pragma unroll
    for (int k = 0; k < 8; ++k) qf[k] = *(const float4*)&ql[k * 32 + s * 4];

    const int nch = (nn + 7) >> 3;          // 8-row chunks
    const int last = s0 + nn - 1;
    const float NEG = -3.402823466e38f;

    float m_run = NEG, l_run = 0.f;
    float4 racc[8] = {};
    float4 xc[8], xn[8];

    int c = w;
    if (c < nch) {
        int node = s0 + c * 8 + j; if (node > last) node = last;
        const float* bp = x + (size_t)node * HID + s * 4;
        #pragma unroll
        for (int k = 0; k < 8; ++k) xc[k] = *(const float4*)(bp + k * 32);
    }
    for (; c < nch; c += 4) {
        if (c + 4 < nch) {
            int node = s0 + (c + 4) * 8 + j; if (node > last) node = last;
            const float* bp = x + (size_t)node * HID + s * 4;
            #pragma unroll
            for (int k = 0; k < 8; ++k) xn[k] = *(const float4*)(bp + k * 32);
        }
        const bool valid = (c * 8 + j) < nn;   // j=0 always valid for c<nch

        float e = 0.f;
        #pragma unroll
        for (int k = 0; k < 8; ++k)
            e += xc[k].x * qf[k].x + xc[k].y * qf[k].y + xc[k].z * qf[k].z + xc[k].w * qf[k].w;
        e += __shfl_xor(e, 1); e += __shfl_xor(e, 2); e += __shfl_xor(e, 4);
        e = valid ? e : NEG;

        float mc = e;
        mc = fmaxf(mc, __shfl_xor(mc, 8));
        mc = fmaxf(mc, __shfl_xor(mc, 16));
        mc = fmaxf(mc, __shfl_xor(mc, 32));
        float m_new = fmaxf(m_run, mc);        // finite: row j=0 is valid
        float alpha = __expf(m_run - m_new);   // first iter: expf(-3.4e38)=0
        float p = valid ? __expf(e - m_new) : 0.f;
        float ps = p;
        ps += __shfl_xor(ps, 8); ps += __shfl_xor(ps, 16); ps += __shfl_xor(ps, 32);
        l_run = l_run * alpha + ps;
        m_run = m_new;
        #pragma unroll
        for (int k = 0; k < 8; ++k) {
            racc[k].x = racc[k].x * alpha + p * xc[k].x;
            racc[k].y = racc[k].y * alpha + p * xc[k].y;
            racc[k].z = racc[k].z * alpha + p * xc[k].z;
            racc[k].w = racc[k].w * alpha + p * xc[k].w;
        }
        #pragma unroll
        for (int k = 0; k < 8; ++k) xc[k] = xn[k];
    }

    // fold racc across the 8 row-slots (lane bits 3..5); once per pass
    #pragma unroll
    for (int k = 0; k < 8; ++k) {
        racc[k].x += __shfl_xor(racc[k].x, 8);
        racc[k].y += __shfl_xor(racc[k].y, 8);
        racc[k].z += __shfl_xor(racc[k].z, 8);
        racc[k].w += __shfl_xor(racc[k].w, 8);
        racc[k].x += __shfl_xor(racc[k].x, 16);
        racc[k].y += __shfl_xor(racc[k].y, 16);
        racc[k].z += __shfl_xor(racc[k].z, 16);
        racc[k].w += __shfl_xor(racc[k].w, 16);
        racc[k].x += __shfl_xor(racc[k].x, 32);
        racc[k].y += __shfl_xor(racc[k].y, 32);
        racc[k].z += __shfl_xor(racc[k].z, 32);
        racc[k].w += __shfl_xor(racc[k].w, 32);
    }
    if (j == 0) {
        #pragma unroll
        for (int k = 0; k < 8; ++k) *(float4*)&red[w][k * 32 + s * 4] = racc[k];
        if (s == 0) { mw[w] = m_run; lw[w] = l_run; }
    }
    __syncthreads();

    // merge the 4 wave-states (empty wave: m=NEG -> factor exp(NEG-M)=0)
    float M = fmaxf(fmaxf(mw[0], mw[1]), fmaxf(mw[2], mw[3]));
    float f0 = __expf(mw[0] - M), f1 = __expf(mw[1] - M);
    float f2 = __expf(mw[2] - M), f3 = __expf(mw[3] - M);
    float L = lw[0] * f0 + lw[1] * f1 + lw[2] * f2 + lw[3] * f3;
    float r = red[0][tid] * f0 + red[1][tid] * f1 + red[2][tid] * f2 + red[3][tid] * f3;
    qs[(size_t)g * 512 + HID + tid] = r / L;     // q_star[:, 256:512] = r
}

// ---------------------------------------------------------------------------
// Cp[z][M x N] = A[M x K-slice] * B[N x K-slice]^T ; 64x64 tile, 4x4 micro,
// b128 LDS reads both operands, global prefetch. grid (N/64, M/64, S).
__global__ __launch_bounds__(256) void gemm_splitk(
    const float* __restrict__ A, int lda,
    const float* __restrict__ B, int ldb,
    float* __restrict__ Cp, int ldc, int KS, size_t slice_stride)
{
    __shared__ float As[16][76];
    __shared__ float Bs[16][76];
    const int tid = threadIdx.x;
    const int tx = tid & 15, ty = tid >> 4;
    const int m0 = blockIdx.y * 64, n0 = blockIdx.x * 64;
    const int kb = blockIdx.z * KS;
    const int r = tid >> 2, kc = (tid & 3) << 2;
    float acc[4][4] = {};

    const float* Ap = &A[(size_t)(m0 + r) * lda + kb + kc];
    const float* Bp = &B[(size_t)(n0 + r) * ldb + kb + kc];
    float4 av = *(const float4*)Ap;
    float4 bv = *(const float4*)Bp;

    for (int k0 = 0; k0 < KS; k0 += 16) {
        As[kc + 0][r] = av.x; As[kc + 1][r] = av.y; As[kc + 2][r] = av.z; As[kc + 3][r] = av.w;
        Bs[kc + 0][r] = bv.x; Bs[kc + 1][r] = bv.y; Bs[kc + 2][r] = bv.z; Bs[kc + 3][r] = bv.w;
        __syncthreads();
        if (k0 + 16 < KS) {
            av = *(const float4*)(Ap + k0 + 16);
            bv = *(const float4*)(Bp + k0 + 16);
        }
        #pragma unroll
        for (int kk = 0; kk < 16; ++kk) {
            float4 a = *(const float4*)&As[kk][ty << 2];
            float4 b = *(const float4*)&Bs[kk][tx << 2];
            acc[0][0] += a.x * b.x; acc[0][1] += a.x * b.y; acc[0][2] += a.x * b.z; acc[0][3] += a.x * b.w;
            acc[1][0] += a.y * b.x; acc[1][1] += a.y * b.y; acc[1][2] += a.y * b.z; acc[1][3] += a.y * b.w;
            acc[2][0] += a.z * b.x; acc[2][1] += a.z * b.y; acc[2][2] += a.z * b.z; acc[2][3] += a.z * b.w;
            acc[3][0] += a.w * b.x; acc[3][1] += a.w * b.y; acc[3][2] += a.w * b.z; acc[3][3] += a.w * b.w;
        }
        __syncthreads();
    }
    float* out = Cp + blockIdx.z * slice_stride;
    #pragma unroll
    for (int i = 0; i < 4; ++i) {
        float4 o = make_float4(acc[i][0], acc[i][1], acc[i][2], acc[i][3]);
        *(float4*)&out[(size_t)(m0 + ty * 4 + i) * ldc + n0 + (tx << 2)] = o;
    }
}

// ---------------------------------------------------------------------------
__global__ __launch_bounds__(256) void finalize_out(
    const float* __restrict__ op, const float* __restrict__ b_out,
    float* __restrict__ out)
{
    int i = blockIdx.x * 256 + threadIdx.x;
    if (i < 512 * 256) {
        float v = op[i] + op[131072 + i] + op[262144 + i] + op[393216 + i] + b_out[i & 255];
        out[i] = v;
    }
}

// ---------------------------------------------------------------------------
extern "C" void kernel_launch(void* const* d_in, const int* in_sizes, int n_in,
                              void* d_out, int out_size, void* d_ws, size_t ws_size,
                              hipStream_t stream)
{
    const float* x     = (const float*)d_in[0];
    const int*   batch = (const int*)d_in[1];
    const float* W_ih  = (const float*)d_in[2];
    const float* W_hh  = (const float*)d_in[3];
    const float* b_ih  = (const float*)d_in[4];
    const float* b_hh  = (const float*)d_in[5];
    const float* W_out = (const float*)d_in[6];
    const float* b_out = (const float*)d_in[7];
    float* out = (float*)d_out;
    const int n = in_sizes[1];
    (void)n_in; (void)out_size; (void)ws_size;

    char* ws = (char*)d_ws;
    float* qs      = (float*)(ws);                  // [512][512]
    float* cs      = (float*)(ws + 0x100000);       // [512][256]
    float* gates_p = (float*)(ws + 0x180000);       // [2][512][1024]
    float* Wcat    = (float*)(ws + 0x580000);       // [1024][512]
    float* bcat    = (float*)(ws + 0x780000);       // [1024]
    int*   starts  = (int*)  (ws + 0x781000);       // [513]
    float* out_p   = (float*)(ws + 0x790000);       // [4][512][256]

    prep_kernel<<<2048, 256, 0, stream>>>(W_ih, W_hh, b_ih, b_hh, Wcat, bcat);
    find_starts<<<3, 256, 0, stream>>>(batch, n, starts);

    for (int step = 0; step < 3; ++step) {
        if (step > 0) {
            gemm_splitk<<<dim3(16, 8, 2), 256, 0, stream>>>(
                qs, 512, Wcat, 512, gates_p, 1024, 256, (size_t)512 * 1024);
        }
        attn_kernel<<<NG, 256, 0, stream>>>(
            x, starts, gates_p, gates_p + (size_t)512 * 1024, bcat, cs, qs, step == 0);
    }
    gemm_splitk<<<dim3(4, 8, 4), 256, 0, stream>>>(
        qs, 512, W_out, 512, out_p, 256, 128, (size_t)512 * 256);
    finalize_out<<<512, 256, 0, stream>>>(out_p, b_out, out);
}